// Round 1
// baseline (3877.205 us; speedup 1.0000x reference)
//
#include <hip/hip_runtime.h>

#define BN_EPS 1e-5f

static inline size_t align_up(size_t x, size_t a) { return (x + a - 1) & ~(a - 1); }

// ---------------- degree / norm precompute ----------------

__global__ void deg_kernel(const int* __restrict__ dst, const float* __restrict__ ew,
                           float* __restrict__ deg, int E) {
    int e = blockIdx.x * blockDim.x + threadIdx.x;
    if (e < E) atomicAdd(&deg[dst[e]], ew[e]);
}

__global__ void dinv_kernel(float* deg, int N) {
    int i = blockIdx.x * blockDim.x + threadIdx.x;
    // +1.0 is the self-loop weight; deg > 0 always
    if (i < N) deg[i] = rsqrtf(deg[i] + 1.0f);
}

__global__ void norm_kernel(const int* __restrict__ src, const int* __restrict__ dst,
                            const float* __restrict__ ew, const float* __restrict__ dinv,
                            float* __restrict__ norm, int E) {
    int e = blockIdx.x * blockDim.x + threadIdx.x;
    if (e < E) norm[e] = dinv[src[e]] * ew[e] * dinv[dst[e]];
}

// ---------------- fp32 GEMM: Y[N x 128] = X[N x K] @ W[K x 128] ----------------
// block = 256 threads, 32 rows/block. Thread (cg = tid&15, r = tid>>4) computes
// rows {r, r+16} x cols [cg*8, cg*8+8). W and the X tile staged in LDS.

template<int K>
__launch_bounds__(256)
__global__ void gemm_kernel(const float* __restrict__ X, const float* __restrict__ W,
                            float* __restrict__ Y, int N) {
    __shared__ float sW[K * 128];
    __shared__ float sX[32 * K];
    for (int i = threadIdx.x; i < K * 32; i += 256)
        ((float4*)sW)[i] = ((const float4*)W)[i];
    int row0 = blockIdx.x * 32;
    constexpr int K4 = K / 4;
    for (int i = threadIdx.x; i < 32 * K4; i += 256) {
        int r = i / K4, c = i - r * K4;
        int row = row0 + r;
        float4 v = make_float4(0.f, 0.f, 0.f, 0.f);
        if (row < N) v = ((const float4*)&X[(size_t)row * K])[c];
        ((float4*)&sX[r * K])[c] = v;
    }
    __syncthreads();

    int cg = threadIdx.x & 15;
    int r  = threadIdx.x >> 4;
    float a0[8] = {0,0,0,0,0,0,0,0};
    float a1[8] = {0,0,0,0,0,0,0,0};
    const float* x0 = &sX[r * K];
    const float* x1 = &sX[(r + 16) * K];
    #pragma unroll 4
    for (int k = 0; k < K; ++k) {
        float xa = x0[k];
        float xb = x1[k];
        float4 w0 = ((const float4*)&sW[k * 128])[cg * 2];
        float4 w1 = ((const float4*)&sW[k * 128])[cg * 2 + 1];
        a0[0] += xa * w0.x; a0[1] += xa * w0.y; a0[2] += xa * w0.z; a0[3] += xa * w0.w;
        a0[4] += xa * w1.x; a0[5] += xa * w1.y; a0[6] += xa * w1.z; a0[7] += xa * w1.w;
        a1[0] += xb * w0.x; a1[1] += xb * w0.y; a1[2] += xb * w0.z; a1[3] += xb * w0.w;
        a1[4] += xb * w1.x; a1[5] += xb * w1.y; a1[6] += xb * w1.z; a1[7] += xb * w1.w;
    }
    int rowA = row0 + r, rowB = row0 + r + 16;
    if (rowA < N) {
        float4* y = (float4*)&Y[(size_t)rowA * 128 + cg * 8];
        y[0] = make_float4(a0[0], a0[1], a0[2], a0[3]);
        y[1] = make_float4(a0[4], a0[5], a0[6], a0[7]);
    }
    if (rowB < N) {
        float4* y = (float4*)&Y[(size_t)rowB * 128 + cg * 8];
        y[0] = make_float4(a1[0], a1[1], a1[2], a1[3]);
        y[1] = make_float4(a1[4], a1[5], a1[6], a1[7]);
    }
}

// ---------------- self-loop init: A[i] = H[i] * dinv[i]^2 ----------------

__global__ void selfloop_kernel(const float* __restrict__ H, const float* __restrict__ dinv,
                                float* __restrict__ A, int N) {
    int idx = blockIdx.x * blockDim.x + threadIdx.x;   // N*32 threads, float4 each
    int node = idx >> 5, l = idx & 31;
    if (node >= N) return;
    float d = dinv[node];
    float w = d * d;
    float4 h = ((const float4*)&H[(size_t)node * 128])[l];
    ((float4*)&A[(size_t)node * 128])[l] = make_float4(h.x * w, h.y * w, h.z * w, h.w * w);
}

// ---------------- edge scatter: A[dst] += H[src] * norm ----------------
// 32 threads per edge, one float4 per thread.

__global__ void scatter_kernel(const int* __restrict__ src, const int* __restrict__ dst,
                               const float* __restrict__ norm, const float* __restrict__ H,
                               float* __restrict__ A, int E) {
    int idx = blockIdx.x * blockDim.x + threadIdx.x;
    int e = idx >> 5, l = idx & 31;
    if (e >= E) return;
    int s = src[e], d = dst[e];
    float w = norm[e];
    float4 h = ((const float4*)&H[(size_t)s * 128])[l];
    float* a = &A[(size_t)d * 128 + l * 4];
    atomicAdd(a + 0, h.x * w);
    atomicAdd(a + 1, h.y * w);
    atomicAdd(a + 2, h.z * w);
    atomicAdd(a + 3, h.w * w);
}

// ---------------- BN(eval) scale/shift precompute ----------------
// value = (agg + b - rm) * (g * rsqrt(rv+eps)) + beta = agg*scale + shift

__global__ void scaleshift_kernel(const float* __restrict__ gamma, const float* __restrict__ beta,
                                  const float* __restrict__ rm, const float* __restrict__ rv,
                                  const float* __restrict__ b,
                                  float* __restrict__ scale, float* __restrict__ shift) {
    int j = threadIdx.x;   // 128 threads
    float sc = gamma[j] * rsqrtf(rv[j] + BN_EPS);
    scale[j] = sc;
    shift[j] = beta[j] + (b[j] - rm[j]) * sc;
}

__global__ void bnrelu_kernel(float* __restrict__ A, const float* __restrict__ scale,
                              const float* __restrict__ shift, int N) {
    int idx = blockIdx.x * blockDim.x + threadIdx.x;   // N*32 threads, float4 each
    int node = idx >> 5, l = idx & 31;
    if (node >= N) return;
    int c = l * 4;
    float4 v = ((float4*)&A[(size_t)node * 128])[l];
    v.x = fmaxf(v.x * scale[c + 0] + shift[c + 0], 0.f);
    v.y = fmaxf(v.y * scale[c + 1] + shift[c + 1], 0.f);
    v.z = fmaxf(v.z * scale[c + 2] + shift[c + 2], 0.f);
    v.w = fmaxf(v.w * scale[c + 3] + shift[c + 3], 0.f);
    ((float4*)&A[(size_t)node * 128])[l] = v;
}

// ---------------- pooling: per-node dot with Wout, segment mean by batch ----------------

__global__ void pool_kernel(const float* __restrict__ H, const int* __restrict__ batch,
                            const float* __restrict__ Wout, float* __restrict__ ssum,
                            float* __restrict__ cnt, int N) {
    int idx = blockIdx.x * blockDim.x + threadIdx.x;
    int node = idx >> 6, l = idx & 63;                 // one wave per node
    if (node >= N) return;
    float2 h = ((const float2*)&H[(size_t)node * 128])[l];
    float2 w = ((const float2*)Wout)[l];
    float s = h.x * w.x + h.y * w.y;
    #pragma unroll
    for (int off = 32; off > 0; off >>= 1) s += __shfl_down(s, off, 64);
    if (l == 0) {
        int g = batch[node];
        atomicAdd(&ssum[g], s);
        atomicAdd(&cnt[g], 1.0f);
    }
}

__global__ void final_kernel(const float* __restrict__ ssum, const float* __restrict__ cnt,
                             const float* __restrict__ bout, float* __restrict__ out, int G) {
    int g = blockIdx.x * blockDim.x + threadIdx.x;
    if (g < G) out[g] = ssum[g] / fmaxf(cnt[g], 1.0f) + bout[0];
}

// ---------------- host launch ----------------

extern "C" void kernel_launch(void* const* d_in, const int* in_sizes, int n_in,
                              void* d_out, int out_size, void* d_ws, size_t ws_size,
                              hipStream_t stream) {
    const float* x     = (const float*)d_in[0];
    const int*   ei    = (const int*)d_in[1];
    const float* ew    = (const float*)d_in[2];
    const int*   batch = (const int*)d_in[3];
    const float* W0 = (const float*)d_in[4];
    const float* b0 = (const float*)d_in[5];
    const float* W1 = (const float*)d_in[6];
    const float* b1 = (const float*)d_in[7];
    const float* W2 = (const float*)d_in[8];
    const float* b2 = (const float*)d_in[9];
    const float* gamma = (const float*)d_in[10];
    const float* beta  = (const float*)d_in[11];
    const float* rmean = (const float*)d_in[12];
    const float* rvar  = (const float*)d_in[13];
    const float* Wout  = (const float*)d_in[14];
    const float* bout  = (const float*)d_in[15];

    const int E = in_sizes[2];
    const int N = in_sizes[3];
    const int D_IN = in_sizes[0] / N;   // 100
    const int G = out_size;

    const int* src = ei;
    const int* dst = ei + E;

    // workspace carve-up
    char* ws = (char*)d_ws;
    size_t off = 0;
    float* dinv = (float*)(ws + off); off = align_up(off + (size_t)N * 4, 256);
    float* norm = (float*)(ws + off); off = align_up(off + (size_t)E * 4, 256);
    float* buf0 = (float*)(ws + off); off = align_up(off + (size_t)N * 128 * 4, 256);
    float* buf1 = (float*)(ws + off); off = align_up(off + (size_t)N * 128 * 4, 256);
    float* ssum = (float*)(ws + off); off = align_up(off + (size_t)G * 4 * 2, 256); // ssum + cnt adjacent
    float* cnt  = ssum + G;
    float* scale = (float*)(ws + off); off = align_up(off + 128 * 4, 256);
    float* shift = (float*)(ws + off); off = align_up(off + 128 * 4, 256);
    (void)ws_size;

    hipMemsetAsync(dinv, 0, (size_t)N * 4, stream);
    hipMemsetAsync(ssum, 0, (size_t)G * 4 * 2, stream);

    int tB = 256;
    deg_kernel<<<(E + tB - 1) / tB, tB, 0, stream>>>(dst, ew, dinv, E);
    dinv_kernel<<<(N + tB - 1) / tB, tB, 0, stream>>>(dinv, N);
    norm_kernel<<<(E + tB - 1) / tB, tB, 0, stream>>>(src, dst, ew, dinv, norm, E);

    const float* Ws[3] = {W0, W1, W2};
    const float* bs[3] = {b0, b1, b2};

    long nthread_node = (long)N * 32;
    int blocks_node = (int)((nthread_node + tB - 1) / tB);
    long nthread_edge = (long)E * 32;
    int blocks_edge = (int)((nthread_edge + tB - 1) / tB);

    for (int l = 0; l < 3; ++l) {
        scaleshift_kernel<<<1, 128, 0, stream>>>(gamma + l * 128, beta + l * 128,
                                                 rmean + l * 128, rvar + l * 128,
                                                 bs[l], scale, shift);
        const float* in = (l == 0) ? x : buf1;
        int gemm_blocks = (N + 31) / 32;
        if (l == 0) {
            if (D_IN == 100)
                gemm_kernel<100><<<gemm_blocks, 256, 0, stream>>>(in, Ws[l], buf0, N);
            else
                gemm_kernel<128><<<gemm_blocks, 256, 0, stream>>>(in, Ws[l], buf0, N);
        } else {
            gemm_kernel<128><<<gemm_blocks, 256, 0, stream>>>(in, Ws[l], buf0, N);
        }
        selfloop_kernel<<<blocks_node, tB, 0, stream>>>(buf0, dinv, buf1, N);
        scatter_kernel<<<blocks_edge, tB, 0, stream>>>(src, dst, norm, buf0, buf1, E);
        bnrelu_kernel<<<blocks_node, tB, 0, stream>>>(buf1, scale, shift, N);
    }

    long nthread_pool = (long)N * 64;
    int blocks_pool = (int)((nthread_pool + tB - 1) / tB);
    pool_kernel<<<blocks_pool, tB, 0, stream>>>(buf1, batch, Wout, ssum, cnt, N);
    final_kernel<<<(G + tB - 1) / tB, tB, 0, stream>>>(ssum, cnt, bout, (float*)d_out, G);
}

// Round 2
// 777.874 us; speedup vs baseline: 4.9844x; 4.9844x over previous
//
#include <hip/hip_runtime.h>

#define BN_EPS 1e-5f

static inline size_t align_up(size_t x, size_t a) { return (x + a - 1) & ~(a - 1); }

// ---------------- histogram: float deg (sum ew) + int count per dst ----------------

__global__ void hist_kernel(const int* __restrict__ dst, const float* __restrict__ ew,
                            float* __restrict__ deg, int* __restrict__ cntc, int E) {
    int e = blockIdx.x * blockDim.x + threadIdx.x;
    if (e < E) {
        int d = dst[e];
        atomicAdd(&deg[d], ew[e]);
        atomicAdd(&cntc[d], 1);
    }
}

__global__ void dinv_kernel(float* deg, int N) {
    int i = blockIdx.x * blockDim.x + threadIdx.x;
    if (i < N) deg[i] = rsqrtf(deg[i] + 1.0f);   // +1 = self-loop weight
}

// ---------------- exclusive scan (3-phase) over cntc[N] -> rowptr/cursor ----------------
// phase 1: block of 256 threads scans 1024 elems; writes per-elem exclusive (intra-block), block total

__global__ void scan1_kernel(const int* __restrict__ cnt, int* __restrict__ excl,
                             int* __restrict__ bsum, int N) {
    __shared__ int lds[256];
    int base = blockIdx.x * 1024;
    int t = threadIdx.x;
    int v[4]; int s = 0;
    #pragma unroll
    for (int j = 0; j < 4; ++j) {
        int idx = base + t * 4 + j;
        v[j] = (idx < N) ? cnt[idx] : 0;
        s += v[j];
    }
    lds[t] = s;
    __syncthreads();
    for (int off = 1; off < 256; off <<= 1) {
        int x = (t >= off) ? lds[t - off] : 0;
        __syncthreads();
        lds[t] += x;
        __syncthreads();
    }
    int run = lds[t] - s;   // exclusive prefix of this thread's chunk within block
    #pragma unroll
    for (int j = 0; j < 4; ++j) {
        int idx = base + t * 4 + j;
        if (idx < N) excl[idx] = run;
        run += v[j];
    }
    if (t == 255) bsum[blockIdx.x] = lds[255];
}

// phase 2: single block exclusive-scans bsum[nb] (nb <= 256)

__global__ void scan2_kernel(int* __restrict__ bsum, int nb) {
    __shared__ int lds[256];
    int t = threadIdx.x;
    int v = (t < nb) ? bsum[t] : 0;
    lds[t] = v;
    __syncthreads();
    for (int off = 1; off < 256; off <<= 1) {
        int x = (t >= off) ? lds[t - off] : 0;
        __syncthreads();
        lds[t] += x;
        __syncthreads();
    }
    if (t < nb) bsum[t] = lds[t] - v;   // exclusive
}

// phase 3: rowptr[idx] = excl[idx] + bsum[block]; cursor same; rowptr[N] = E

__global__ void scan3_kernel(const int* __restrict__ excl, const int* __restrict__ bsum,
                             int* __restrict__ rowptr, int* __restrict__ cursor, int N, int E) {
    int idx = blockIdx.x * blockDim.x + threadIdx.x;
    if (idx < N) {
        int v = excl[idx] + bsum[idx >> 10];
        rowptr[idx] = v;
        cursor[idx] = v;
    }
    if (idx == 0) rowptr[N] = E;
}

// ---------------- bucket edges by dst: edges[pos] = (src, norm) ----------------

__global__ void bucket_kernel(const int* __restrict__ src, const int* __restrict__ dst,
                              const float* __restrict__ ew, const float* __restrict__ dinv,
                              int* __restrict__ cursor, int2* __restrict__ edges, int E) {
    int e = blockIdx.x * blockDim.x + threadIdx.x;
    if (e >= E) return;
    int s = src[e], d = dst[e];
    float nrm = dinv[s] * ew[e] * dinv[d];
    int pos = atomicAdd(&cursor[d], 1);
    edges[pos] = make_int2(s, __float_as_int(nrm));
}

// ---------------- fp32 GEMM: Y[N x 128] = X[N x K] @ W[K x 128] ----------------

template<int K>
__launch_bounds__(256)
__global__ void gemm_kernel(const float* __restrict__ X, const float* __restrict__ W,
                            float* __restrict__ Y, int N) {
    __shared__ float sW[K * 128];
    __shared__ float sX[32 * K];
    for (int i = threadIdx.x; i < K * 32; i += 256)
        ((float4*)sW)[i] = ((const float4*)W)[i];
    int row0 = blockIdx.x * 32;
    constexpr int K4 = K / 4;
    for (int i = threadIdx.x; i < 32 * K4; i += 256) {
        int r = i / K4, c = i - r * K4;
        int row = row0 + r;
        float4 v = make_float4(0.f, 0.f, 0.f, 0.f);
        if (row < N) v = ((const float4*)&X[(size_t)row * K])[c];
        ((float4*)&sX[r * K])[c] = v;
    }
    __syncthreads();

    int cg = threadIdx.x & 15;
    int r  = threadIdx.x >> 4;
    float a0[8] = {0,0,0,0,0,0,0,0};
    float a1[8] = {0,0,0,0,0,0,0,0};
    const float* x0 = &sX[r * K];
    const float* x1 = &sX[(r + 16) * K];
    #pragma unroll 4
    for (int k = 0; k < K; ++k) {
        float xa = x0[k];
        float xb = x1[k];
        float4 w0 = ((const float4*)&sW[k * 128])[cg * 2];
        float4 w1 = ((const float4*)&sW[k * 128])[cg * 2 + 1];
        a0[0] += xa * w0.x; a0[1] += xa * w0.y; a0[2] += xa * w0.z; a0[3] += xa * w0.w;
        a0[4] += xa * w1.x; a0[5] += xa * w1.y; a0[6] += xa * w1.z; a0[7] += xa * w1.w;
        a1[0] += xb * w0.x; a1[1] += xb * w0.y; a1[2] += xb * w0.z; a1[3] += xb * w0.w;
        a1[4] += xb * w1.x; a1[5] += xb * w1.y; a1[6] += xb * w1.z; a1[7] += xb * w1.w;
    }
    int rowA = row0 + r, rowB = row0 + r + 16;
    if (rowA < N) {
        float4* y = (float4*)&Y[(size_t)rowA * 128 + cg * 8];
        y[0] = make_float4(a0[0], a0[1], a0[2], a0[3]);
        y[1] = make_float4(a0[4], a0[5], a0[6], a0[7]);
    }
    if (rowB < N) {
        float4* y = (float4*)&Y[(size_t)rowB * 128 + cg * 8];
        y[0] = make_float4(a1[0], a1[1], a1[2], a1[3]);
        y[1] = make_float4(a1[4], a1[5], a1[6], a1[7]);
    }
}

// ---------------- BN(eval) scale/shift precompute ----------------

__global__ void scaleshift_kernel(const float* __restrict__ gamma, const float* __restrict__ beta,
                                  const float* __restrict__ rm, const float* __restrict__ rv,
                                  const float* __restrict__ b,
                                  float* __restrict__ scale, float* __restrict__ shift) {
    int j = threadIdx.x;   // 128 threads
    float sc = gamma[j] * rsqrtf(rv[j] + BN_EPS);
    scale[j] = sc;
    shift[j] = beta[j] + (b[j] - rm[j]) * sc;
}

// ---------------- fused aggregation: CSR gather + self-loop + BN + ReLU ----------------
// one wave (64 lanes) per dst node, float2 per lane.

__launch_bounds__(256)
__global__ void agg_kernel(const float* __restrict__ H, const int2* __restrict__ edges,
                           const int* __restrict__ rowptr, const float* __restrict__ dinv,
                           const float* __restrict__ scale, const float* __restrict__ shift,
                           float* __restrict__ out, int N) {
    int idx = blockIdx.x * blockDim.x + threadIdx.x;
    int node = idx >> 6, lane = idx & 63;
    if (node >= N) return;

    float d = dinv[node];
    float w0 = d * d;
    float2 h = ((const float2*)&H[(size_t)node * 128])[lane];
    float ax = h.x * w0, ay = h.y * w0;

    int beg = rowptr[node], end = rowptr[node + 1];
    for (int base = beg; base < end; base += 64) {
        int m = end - base; if (m > 64) m = 64;
        int2 pr = make_int2(0, 0);
        if (lane < m) pr = edges[base + lane];
        for (int j = 0; j < m; ++j) {
            int   s = __shfl(pr.x, j, 64);
            float w = __int_as_float(__shfl(pr.y, j, 64));
            float2 hs = ((const float2*)&H[(size_t)s * 128])[lane];
            ax += hs.x * w;
            ay += hs.y * w;
        }
    }

    int c = lane * 2;
    float2 sc = ((const float2*)scale)[lane];
    float2 sh = ((const float2*)shift)[lane];
    float2 o;
    o.x = fmaxf(ax * sc.x + sh.x, 0.f);
    o.y = fmaxf(ay * sc.y + sh.y, 0.f);
    ((float2*)&out[(size_t)node * 128])[lane] = o;
    (void)c;
}

// ---------------- pooling ----------------

__global__ void pool_kernel(const float* __restrict__ H, const int* __restrict__ batch,
                            const float* __restrict__ Wout, float* __restrict__ ssum,
                            float* __restrict__ cnt, int N) {
    int idx = blockIdx.x * blockDim.x + threadIdx.x;
    int node = idx >> 6, l = idx & 63;
    if (node >= N) return;
    float2 h = ((const float2*)&H[(size_t)node * 128])[l];
    float2 w = ((const float2*)Wout)[l];
    float s = h.x * w.x + h.y * w.y;
    #pragma unroll
    for (int off = 32; off > 0; off >>= 1) s += __shfl_down(s, off, 64);
    if (l == 0) {
        int g = batch[node];
        atomicAdd(&ssum[g], s);
        atomicAdd(&cnt[g], 1.0f);
    }
}

__global__ void final_kernel(const float* __restrict__ ssum, const float* __restrict__ cnt,
                             const float* __restrict__ bout, float* __restrict__ out, int G) {
    int g = blockIdx.x * blockDim.x + threadIdx.x;
    if (g < G) out[g] = ssum[g] / fmaxf(cnt[g], 1.0f) + bout[0];
}

// ---------------- host launch ----------------

extern "C" void kernel_launch(void* const* d_in, const int* in_sizes, int n_in,
                              void* d_out, int out_size, void* d_ws, size_t ws_size,
                              hipStream_t stream) {
    const float* x     = (const float*)d_in[0];
    const int*   ei    = (const int*)d_in[1];
    const float* ew    = (const float*)d_in[2];
    const int*   batch = (const int*)d_in[3];
    const float* W0 = (const float*)d_in[4];
    const float* b0 = (const float*)d_in[5];
    const float* W1 = (const float*)d_in[6];
    const float* b1 = (const float*)d_in[7];
    const float* W2 = (const float*)d_in[8];
    const float* b2 = (const float*)d_in[9];
    const float* gamma = (const float*)d_in[10];
    const float* beta  = (const float*)d_in[11];
    const float* rmean = (const float*)d_in[12];
    const float* rvar  = (const float*)d_in[13];
    const float* Wout  = (const float*)d_in[14];
    const float* bout  = (const float*)d_in[15];

    const int E = in_sizes[2];
    const int N = in_sizes[3];
    const int D_IN = in_sizes[0] / N;   // 100
    const int G = out_size;

    const int* src = ei;
    const int* dst = ei + E;

    // workspace carve-up
    char* ws = (char*)d_ws;
    size_t off = 0;
    float* dinv  = (float*)(ws + off); off = align_up(off + (size_t)N * 4, 256);
    int* cntc    = (int*)(ws + off);   off = align_up(off + (size_t)N * 4, 256);
    int* excl    = (int*)(ws + off);   off = align_up(off + (size_t)N * 4, 256);
    int* rowptr  = (int*)(ws + off);   off = align_up(off + ((size_t)N + 1) * 4, 256);
    int* cursor  = (int*)(ws + off);   off = align_up(off + (size_t)N * 4, 256);
    int* bsum    = (int*)(ws + off);   off = align_up(off + 256 * 4, 256);
    int2* edges  = (int2*)(ws + off);  off = align_up(off + (size_t)E * 8, 256);
    float* buf0  = (float*)(ws + off); off = align_up(off + (size_t)N * 128 * 4, 256);
    float* buf1  = (float*)(ws + off); off = align_up(off + (size_t)N * 128 * 4, 256);
    float* ssum  = (float*)(ws + off); off = align_up(off + (size_t)G * 4 * 2, 256);
    float* cnt   = ssum + G;
    float* scale = (float*)(ws + off); off = align_up(off + 128 * 4, 256);
    float* shift = (float*)(ws + off); off = align_up(off + 128 * 4, 256);
    (void)ws_size;

    hipMemsetAsync(dinv, 0, (size_t)N * 4, stream);
    hipMemsetAsync(cntc, 0, (size_t)N * 4, stream);
    hipMemsetAsync(ssum, 0, (size_t)G * 4 * 2, stream);

    const int tB = 256;
    hist_kernel<<<(E + tB - 1) / tB, tB, 0, stream>>>(dst, ew, dinv, cntc, E);
    dinv_kernel<<<(N + tB - 1) / tB, tB, 0, stream>>>(dinv, N);

    int nb = (N + 1023) / 1024;   // 98 for N=100000
    scan1_kernel<<<nb, 256, 0, stream>>>(cntc, excl, bsum, N);
    scan2_kernel<<<1, 256, 0, stream>>>(bsum, nb);
    scan3_kernel<<<(N + tB - 1) / tB, tB, 0, stream>>>(excl, bsum, rowptr, cursor, N, E);
    bucket_kernel<<<(E + tB - 1) / tB, tB, 0, stream>>>(src, dst, ew, dinv, cursor, edges, E);

    const float* Ws[3] = {W0, W1, W2};
    const float* bs[3] = {b0, b1, b2};

    long nthread_node = (long)N * 64;
    int blocks_node = (int)((nthread_node + tB - 1) / tB);

    for (int l = 0; l < 3; ++l) {
        scaleshift_kernel<<<1, 128, 0, stream>>>(gamma + l * 128, beta + l * 128,
                                                 rmean + l * 128, rvar + l * 128,
                                                 bs[l], scale, shift);
        const float* in = (l == 0) ? x : buf1;
        int gemm_blocks = (N + 31) / 32;
        if (l == 0) {
            if (D_IN == 100)
                gemm_kernel<100><<<gemm_blocks, 256, 0, stream>>>(in, Ws[l], buf0, N);
            else
                gemm_kernel<128><<<gemm_blocks, 256, 0, stream>>>(in, Ws[l], buf0, N);
        } else {
            gemm_kernel<128><<<gemm_blocks, 256, 0, stream>>>(in, Ws[l], buf0, N);
        }
        agg_kernel<<<blocks_node, tB, 0, stream>>>(buf0, edges, rowptr, dinv,
                                                   scale, shift, buf1, N);
    }

    pool_kernel<<<blocks_node, tB, 0, stream>>>(buf1, batch, Wout, ssum, cnt, N);
    final_kernel<<<(G + tB - 1) / tB, tB, 0, stream>>>(ssum, cnt, bout, (float*)d_out, G);
}

// Round 3
// 670.395 us; speedup vs baseline: 5.7835x; 1.1603x over previous
//
#include <hip/hip_runtime.h>

#define BN_EPS 1e-5f

static inline size_t align_up(size_t x, size_t a) { return (x + a - 1) & ~(a - 1); }

// ---------------- histogram: float deg (sum ew) + int count per dst ----------------

__global__ void hist_kernel(const int* __restrict__ dst, const float* __restrict__ ew,
                            float* __restrict__ deg, int* __restrict__ cntc, int E) {
    int e = blockIdx.x * blockDim.x + threadIdx.x;
    if (e < E) {
        int d = dst[e];
        atomicAdd(&deg[d], ew[e]);
        atomicAdd(&cntc[d], 1);
    }
}

__global__ void dinv_kernel(float* deg, int N) {
    int i = blockIdx.x * blockDim.x + threadIdx.x;
    if (i < N) deg[i] = rsqrtf(deg[i] + 1.0f);   // +1 = self-loop weight
}

// ---------------- exclusive scan (3-phase) over cntc[N] -> rowptr/cursor ----------------

__global__ void scan1_kernel(const int* __restrict__ cnt, int* __restrict__ excl,
                             int* __restrict__ bsum, int N) {
    __shared__ int lds[256];
    int base = blockIdx.x * 1024;
    int t = threadIdx.x;
    int v[4]; int s = 0;
    #pragma unroll
    for (int j = 0; j < 4; ++j) {
        int idx = base + t * 4 + j;
        v[j] = (idx < N) ? cnt[idx] : 0;
        s += v[j];
    }
    lds[t] = s;
    __syncthreads();
    for (int off = 1; off < 256; off <<= 1) {
        int x = (t >= off) ? lds[t - off] : 0;
        __syncthreads();
        lds[t] += x;
        __syncthreads();
    }
    int run = lds[t] - s;
    #pragma unroll
    for (int j = 0; j < 4; ++j) {
        int idx = base + t * 4 + j;
        if (idx < N) excl[idx] = run;
        run += v[j];
    }
    if (t == 255) bsum[blockIdx.x] = lds[255];
}

__global__ void scan2_kernel(int* __restrict__ bsum, int nb) {
    __shared__ int lds[256];
    int t = threadIdx.x;
    int v = (t < nb) ? bsum[t] : 0;
    lds[t] = v;
    __syncthreads();
    for (int off = 1; off < 256; off <<= 1) {
        int x = (t >= off) ? lds[t - off] : 0;
        __syncthreads();
        lds[t] += x;
        __syncthreads();
    }
    if (t < nb) bsum[t] = lds[t] - v;
}

__global__ void scan3_kernel(const int* __restrict__ excl, const int* __restrict__ bsum,
                             int* __restrict__ rowptr, int* __restrict__ cursor, int N, int E) {
    int idx = blockIdx.x * blockDim.x + threadIdx.x;
    if (idx < N) {
        int v = excl[idx] + bsum[idx >> 10];
        rowptr[idx] = v;
        cursor[idx] = v;
    }
    if (idx == 0) rowptr[N] = E;
}

// ---------------- bucket edges by dst: edges[pos] = (src, norm) ----------------

__global__ void bucket_kernel(const int* __restrict__ src, const int* __restrict__ dst,
                              const float* __restrict__ ew, const float* __restrict__ dinv,
                              int* __restrict__ cursor, int2* __restrict__ edges, int E) {
    int e = blockIdx.x * blockDim.x + threadIdx.x;
    if (e >= E) return;
    int s = src[e], d = dst[e];
    float nrm = dinv[s] * ew[e] * dinv[d];
    int pos = atomicAdd(&cursor[d], 1);
    edges[pos] = make_int2(s, __float_as_int(nrm));
}

// ---------------- fp32 GEMM: Y[N x 128] = X[N x K] @ W[K x 128] ----------------

template<int K>
__launch_bounds__(256)
__global__ void gemm_kernel(const float* __restrict__ X, const float* __restrict__ W,
                            float* __restrict__ Y, int N) {
    __shared__ float sW[K * 128];
    __shared__ float sX[32 * K];
    for (int i = threadIdx.x; i < K * 32; i += 256)
        ((float4*)sW)[i] = ((const float4*)W)[i];
    int row0 = blockIdx.x * 32;
    constexpr int K4 = K / 4;
    for (int i = threadIdx.x; i < 32 * K4; i += 256) {
        int r = i / K4, c = i - r * K4;
        int row = row0 + r;
        float4 v = make_float4(0.f, 0.f, 0.f, 0.f);
        if (row < N) v = ((const float4*)&X[(size_t)row * K])[c];
        ((float4*)&sX[r * K])[c] = v;
    }
    __syncthreads();

    int cg = threadIdx.x & 15;
    int r  = threadIdx.x >> 4;
    float a0[8] = {0,0,0,0,0,0,0,0};
    float a1[8] = {0,0,0,0,0,0,0,0};
    const float* x0 = &sX[r * K];
    const float* x1 = &sX[(r + 16) * K];
    #pragma unroll 4
    for (int k = 0; k < K; ++k) {
        float xa = x0[k];
        float xb = x1[k];
        float4 w0 = ((const float4*)&sW[k * 128])[cg * 2];
        float4 w1 = ((const float4*)&sW[k * 128])[cg * 2 + 1];
        a0[0] += xa * w0.x; a0[1] += xa * w0.y; a0[2] += xa * w0.z; a0[3] += xa * w0.w;
        a0[4] += xa * w1.x; a0[5] += xa * w1.y; a0[6] += xa * w1.z; a0[7] += xa * w1.w;
        a1[0] += xb * w0.x; a1[1] += xb * w0.y; a1[2] += xb * w0.z; a1[3] += xb * w0.w;
        a1[4] += xb * w1.x; a1[5] += xb * w1.y; a1[6] += xb * w1.z; a1[7] += xb * w1.w;
    }
    int rowA = row0 + r, rowB = row0 + r + 16;
    if (rowA < N) {
        float4* y = (float4*)&Y[(size_t)rowA * 128 + cg * 8];
        y[0] = make_float4(a0[0], a0[1], a0[2], a0[3]);
        y[1] = make_float4(a0[4], a0[5], a0[6], a0[7]);
    }
    if (rowB < N) {
        float4* y = (float4*)&Y[(size_t)rowB * 128 + cg * 8];
        y[0] = make_float4(a1[0], a1[1], a1[2], a1[3]);
        y[1] = make_float4(a1[4], a1[5], a1[6], a1[7]);
    }
}

// ---------------- BN(eval) scale/shift precompute ----------------

__global__ void scaleshift_kernel(const float* __restrict__ gamma, const float* __restrict__ beta,
                                  const float* __restrict__ rm, const float* __restrict__ rv,
                                  const float* __restrict__ b,
                                  float* __restrict__ scale, float* __restrict__ shift) {
    int j = threadIdx.x;   // 128 threads
    float sc = gamma[j] * rsqrtf(rv[j] + BN_EPS);
    scale[j] = sc;
    shift[j] = beta[j] + (b[j] - rm[j]) * sc;
}

// ---------------- fused aggregation: CSR gather + self-loop + BN + ReLU ----------------

__launch_bounds__(256)
__global__ void agg_kernel(const float* __restrict__ H, const int2* __restrict__ edges,
                           const int* __restrict__ rowptr, const float* __restrict__ dinv,
                           const float* __restrict__ scale, const float* __restrict__ shift,
                           float* __restrict__ out, int N) {
    int idx = blockIdx.x * blockDim.x + threadIdx.x;
    int node = idx >> 6, lane = idx & 63;
    if (node >= N) return;

    float d = dinv[node];
    float w0 = d * d;
    float2 h = ((const float2*)&H[(size_t)node * 128])[lane];
    float ax = h.x * w0, ay = h.y * w0;

    int beg = rowptr[node], end = rowptr[node + 1];
    for (int base = beg; base < end; base += 64) {
        int m = end - base; if (m > 64) m = 64;
        int2 pr = make_int2(0, 0);
        if (lane < m) pr = edges[base + lane];
        for (int j = 0; j < m; ++j) {
            int   s = __shfl(pr.x, j, 64);
            float w = __int_as_float(__shfl(pr.y, j, 64));
            float2 hs = ((const float2*)&H[(size_t)s * 128])[lane];
            ax += hs.x * w;
            ay += hs.y * w;
        }
    }

    float2 sc = ((const float2*)scale)[lane];
    float2 sh = ((const float2*)shift)[lane];
    float2 o;
    o.x = fmaxf(ax * sc.x + sh.x, 0.f);
    o.y = fmaxf(ay * sc.y + sh.y, 0.f);
    ((float2*)&out[(size_t)node * 128])[lane] = o;
}

// ---------------- pooling: graph boundaries + per-graph block reduction ----------------
// batch is sorted. gstart[g] = first node of graph g; gstart[G] = N. Empty graphs ok.

__global__ void bounds_kernel(const int* __restrict__ batch, int* __restrict__ gstart,
                              int N, int G) {
    int i = blockIdx.x * blockDim.x + threadIdx.x;
    if (i >= N) return;
    int b = batch[i];
    int prev = (i == 0) ? -1 : batch[i - 1];
    for (int g = prev + 1; g <= b; ++g) gstart[g] = i;
    if (i == N - 1) {
        for (int g = b + 1; g <= G; ++g) gstart[g] = N;
    }
}

// one block (256 threads) per graph: sum h over node range, dot Wout, mean, +bout
__launch_bounds__(256)
__global__ void pool2_kernel(const float* __restrict__ H, const int* __restrict__ gstart,
                             const float* __restrict__ Wout, const float* __restrict__ bout,
                             float* __restrict__ out, int G) {
    int g = blockIdx.x;
    int beg = gstart[g], end = gstart[g + 1];
    int t = threadIdx.x;
    int c = t & 127;        // channel
    int half = t >> 7;      // node parity
    float acc = 0.f;
    for (int n = beg + half; n < end; n += 2)
        acc += H[(size_t)n * 128 + c];
    __shared__ float lds[256];
    lds[t] = acc * Wout[c];
    __syncthreads();
    // 256 -> 64
    if (t < 64) lds[t] = lds[t] + lds[t + 64] + lds[t + 128] + lds[t + 192];
    __syncthreads();
    if (t < 64) {
        float s = lds[t];
        #pragma unroll
        for (int off = 32; off > 0; off >>= 1) s += __shfl_down(s, off, 64);
        if (t == 0) {
            float cntf = (float)(end - beg);
            out[g] = s / fmaxf(cntf, 1.0f) + bout[0];
        }
    }
}

// ---------------- host launch ----------------

extern "C" void kernel_launch(void* const* d_in, const int* in_sizes, int n_in,
                              void* d_out, int out_size, void* d_ws, size_t ws_size,
                              hipStream_t stream) {
    const float* x     = (const float*)d_in[0];
    const int*   ei    = (const int*)d_in[1];
    const float* ew    = (const float*)d_in[2];
    const int*   batch = (const int*)d_in[3];
    const float* W0 = (const float*)d_in[4];
    const float* b0 = (const float*)d_in[5];
    const float* W1 = (const float*)d_in[6];
    const float* b1 = (const float*)d_in[7];
    const float* W2 = (const float*)d_in[8];
    const float* b2 = (const float*)d_in[9];
    const float* gamma = (const float*)d_in[10];
    const float* beta  = (const float*)d_in[11];
    const float* rmean = (const float*)d_in[12];
    const float* rvar  = (const float*)d_in[13];
    const float* Wout  = (const float*)d_in[14];
    const float* bout  = (const float*)d_in[15];

    const int E = in_sizes[2];
    const int N = in_sizes[3];
    const int D_IN = in_sizes[0] / N;   // 100
    const int G = out_size;

    const int* src = ei;
    const int* dst = ei + E;

    // workspace carve-up
    char* ws = (char*)d_ws;
    size_t off = 0;
    float* dinv  = (float*)(ws + off); off = align_up(off + (size_t)N * 4, 256);
    int* cntc    = (int*)(ws + off);   off = align_up(off + (size_t)N * 4, 256);
    int* excl    = (int*)(ws + off);   off = align_up(off + (size_t)N * 4, 256);
    int* rowptr  = (int*)(ws + off);   off = align_up(off + ((size_t)N + 1) * 4, 256);
    int* cursor  = (int*)(ws + off);   off = align_up(off + (size_t)N * 4, 256);
    int* bsum    = (int*)(ws + off);   off = align_up(off + 256 * 4, 256);
    int* gstart  = (int*)(ws + off);   off = align_up(off + ((size_t)G + 1) * 4, 256);
    int2* edges  = (int2*)(ws + off);  off = align_up(off + (size_t)E * 8, 256);
    float* buf0  = (float*)(ws + off); off = align_up(off + (size_t)N * 128 * 4, 256);
    float* buf1  = (float*)(ws + off); off = align_up(off + (size_t)N * 128 * 4, 256);
    float* scale = (float*)(ws + off); off = align_up(off + 128 * 4, 256);
    float* shift = (float*)(ws + off); off = align_up(off + 128 * 4, 256);
    (void)ws_size;

    hipMemsetAsync(dinv, 0, (size_t)N * 4, stream);
    hipMemsetAsync(cntc, 0, (size_t)N * 4, stream);

    const int tB = 256;
    hist_kernel<<<(E + tB - 1) / tB, tB, 0, stream>>>(dst, ew, dinv, cntc, E);
    dinv_kernel<<<(N + tB - 1) / tB, tB, 0, stream>>>(dinv, N);

    int nb = (N + 1023) / 1024;
    scan1_kernel<<<nb, 256, 0, stream>>>(cntc, excl, bsum, N);
    scan2_kernel<<<1, 256, 0, stream>>>(bsum, nb);
    scan3_kernel<<<(N + tB - 1) / tB, tB, 0, stream>>>(excl, bsum, rowptr, cursor, N, E);
    bucket_kernel<<<(E + tB - 1) / tB, tB, 0, stream>>>(src, dst, ew, dinv, cursor, edges, E);
    bounds_kernel<<<(N + tB - 1) / tB, tB, 0, stream>>>(batch, gstart, N, G);

    const float* Ws[3] = {W0, W1, W2};
    const float* bs[3] = {b0, b1, b2};

    long nthread_node = (long)N * 64;
    int blocks_node = (int)((nthread_node + tB - 1) / tB);

    for (int l = 0; l < 3; ++l) {
        scaleshift_kernel<<<1, 128, 0, stream>>>(gamma + l * 128, beta + l * 128,
                                                 rmean + l * 128, rvar + l * 128,
                                                 bs[l], scale, shift);
        const float* in = (l == 0) ? x : buf1;
        int gemm_blocks = (N + 31) / 32;
        if (l == 0) {
            if (D_IN == 100)
                gemm_kernel<100><<<gemm_blocks, 256, 0, stream>>>(in, Ws[l], buf0, N);
            else
                gemm_kernel<128><<<gemm_blocks, 256, 0, stream>>>(in, Ws[l], buf0, N);
        } else {
            gemm_kernel<128><<<gemm_blocks, 256, 0, stream>>>(in, Ws[l], buf0, N);
        }
        agg_kernel<<<blocks_node, tB, 0, stream>>>(buf0, edges, rowptr, dinv,
                                                   scale, shift, buf1, N);
    }

    pool2_kernel<<<G, 256, 0, stream>>>(buf1, gstart, Wout, bout, (float*)d_out, G);
}